// Round 19
// baseline (425.771 us; speedup 1.0000x reference)
//
#include <hip/hip_runtime.h>
#include <hip/hip_bf16.h>
#include <math.h>

#define NF 2048
#define NS 32768
#define BB 256
#define TEMP_INV 20.0f
#define MOM 0.2f

typedef __attribute__((ext_vector_type(4))) float floatx4;
typedef __attribute__((ext_vector_type(8))) short short8;
typedef __attribute__((ext_vector_type(4))) short short4v;

__device__ inline short f2bf(float f) {
    return __builtin_bit_cast(short, __float2bfloat16(f));
}

// Non-temporal 16B store (used at 16B-ALIGNED addresses only).
__device__ inline void st4u(float* p, floatx4 v) {
    asm volatile("global_store_dwordx4 %0, %1, off nt"
                 :: "v"(p), "v"(v));
}

// Non-temporal feature load: zero-reuse stream must NOT allocate in L2,
// so the 1MB A-matrix stays L2-resident (A is re-read 512x per bank).
__device__ inline floatx4 ntl(const float* p) {
    return __builtin_nontemporal_load(reinterpret_cast<const floatx4*>(p));
}

// Block-wide sum with broadcast to all threads. Deterministic order.
__device__ float blockSum(float v, float* s) {
    int lane = threadIdx.x & 63;
    int w = threadIdx.x >> 6;
    int nw = blockDim.x >> 6;
#pragma unroll
    for (int m = 32; m >= 1; m >>= 1) v += __shfl_xor(v, m);
    __syncthreads();
    if (lane == 0) s[w] = v;
    __syncthreads();
    float tot = s[0];
    for (int i = 1; i < nw; ++i) tot += s[i];
    return tot;
}

// grid (256, 3), block 256. Pair p: student d_in[p], teacher d_in[p+3].
// Fused: normalize student+teacher, ld term, bf16 fragment-order xb,
// AND the exact f32 target logit dot(x_b, F[y_b]) (was k_tgt).
// Teacher normalized rows are NOT stored (only used for ld, computed here).
__global__ __launch_bounds__(256) void k_norm_ld(
    const float* i0, const float* i1, const float* i2,
    const float* i3, const float* i4, const float* i5,
    const float* f0, const float* f1, const float* f2,
    const int* targets,
    float* xn, short* xb, float* ldp, float* tgt) {
    int p = blockIdx.y;
    int b = blockIdx.x;
    const float* S = (p == 0 ? i0 : p == 1 ? i1 : i2) + (size_t)b * NF;
    const float* T = (p == 0 ? i3 : p == 1 ? i4 : i5) + (size_t)b * NF;
    __shared__ float red[8];
    int tid = threadIdx.x;

    float4 s0 = ((const float4*)S)[tid * 2];
    float4 s1 = ((const float4*)S)[tid * 2 + 1];
    float4 t0 = ((const float4*)T)[tid * 2];
    float4 t1 = ((const float4*)T)[tid * 2 + 1];

    float ssS = s0.x*s0.x + s0.y*s0.y + s0.z*s0.z + s0.w*s0.w
              + s1.x*s1.x + s1.y*s1.y + s1.z*s1.z + s1.w*s1.w;
    float ssT = t0.x*t0.x + t0.y*t0.y + t0.z*t0.z + t0.w*t0.w
              + t1.x*t1.x + t1.y*t1.y + t1.z*t1.z + t1.w*t1.w;
    float totS = blockSum(ssS, red);
    float totT = blockSum(ssT, red);
    float invS = 1.0f / sqrtf(totS);
    float invT = 1.0f / sqrtf(totT);

    float xs[8] = { s0.x*invS, s0.y*invS, s0.z*invS, s0.w*invS,
                    s1.x*invS, s1.y*invS, s1.z*invS, s1.w*invS };
    float xt[8] = { t0.x*invT, t0.y*invT, t0.z*invT, t0.w*invT,
                    t1.x*invT, t1.y*invT, t1.z*invT, t1.w*invT };

    float* xns = xn + (size_t)p * BB * NF + (size_t)b * NF + tid * 8;
    ((float4*)xns)[0] = make_float4(xs[0], xs[1], xs[2], xs[3]);
    ((float4*)xns)[1] = make_float4(xs[4], xs[5], xs[6], xs[7]);

    short8 bfv;
#pragma unroll
    for (int j = 0; j < 8; ++j) bfv[j] = f2bf(xs[j]);
    {
        int rb = b >> 4, l15r = b & 15;
        int kb = tid >> 2, lg = tid & 3;
        size_t flat = ((size_t)(rb * 64 + kb) * 64 + lg * 16 + l15r) * 8;
        *(short8*)(xb + (size_t)p * BB * NF + flat) = bfv;
    }

    float ld = 0;
#pragma unroll
    for (int j = 0; j < 8; ++j) { float d = xs[j] - xt[j]; ld += d * d; }
    float ldt = blockSum(ld, red);
    if (tid == 0) ldp[p * BB + b] = ldt;

    // fused target logit: dot(x_b, F[y_b]) * 20, exact f32
    const float* Fy = (p == 0 ? f0 : p == 1 ? f1 : f2)
                      + (size_t)targets[b] * NF + tid * 8;
    float4 g0 = ((const float4*)Fy)[0];
    float4 g1 = ((const float4*)Fy)[1];
    float dp = xs[0]*g0.x + xs[1]*g0.y + xs[2]*g0.z + xs[3]*g0.w
             + xs[4]*g1.x + xs[5]*g1.y + xs[6]*g1.z + xs[7]*g1.w;
    float dtot = blockSum(dp, red);
    if (tid == 0) tgt[p * BB + b] = dtot * TEMP_INV;
}

// grid (512, 3), block 512 (8 waves). Per block: 64 feature rows, full M=256.
// R17's proven config restored: __launch_bounds__(512,2) (2 blocks/CU).
// nt feature loads (A stays L2-resident) + in-register realigned nt stores.
__global__ __launch_bounds__(512, 2) void k_gemm(
    const float* f0, const float* f1, const float* f2,
    const short* xb, float* outb, float* spart) {
    int bank = blockIdx.y;
    const float* F = bank == 0 ? f0 : bank == 1 ? f1 : f2;
    const short* X = xb + (size_t)bank * BB * NF;
    float* C = outb + (size_t)bank * ((size_t)NS * NF);
    int n0 = blockIdx.x * 64;

    __shared__ short Bs[2][64][136];   // 2 x 17408B

    int tid = threadIdx.x;
    int lane = tid & 63, wave = tid >> 6;
    int l15 = lane & 15, lg = lane >> 4;
    int rrow = tid >> 5;               // 0..15
    int h = tid & 31;                  // lane within half-wave = chunk index
    int rcol = h * 4;                  // float col, lane-contiguous

    const float* Fb = F + (size_t)(n0 + rrow) * NF + rcol;
    float* CbR = C + (size_t)(n0 + rrow) * NF;   // row base (no col)
    // fragment-ordered A: rb0 = wave*2, rb1 = wave*2+1; stride per kb = 512
    const short* A0 = X + (size_t)(wave * 2) * 32768 + (size_t)lane * 8;
    const short* A1 = A0 + 32768;

    floatx4 acc[2][4];
#pragma unroll
    for (int mf = 0; mf < 2; ++mf)
#pragma unroll
        for (int nf = 0; nf < 4; ++nf) acc[mf][nf] = (floatx4){0.f, 0.f, 0.f, 0.f};

    // aligned copy-out of one row-segment chunk (j, kbase) from regs v
    auto store_seg = [&](int j, int kbase, floatx4 v) {
        floatx4 st;
        st[0] = v[3];
        st[1] = __shfl_down(v[0], 1);
        st[2] = __shfl_down(v[1], 1);
        st[3] = __shfl_down(v[2], 1);
        float* RS = CbR + (size_t)j * 16 * NF + kbase;
        if (h < 31) st4u(RS + 4 * h + 3, st);
        if (h == 0) { RS[0] = v[0]; RS[1] = v[1]; RS[2] = v[2]; }
        else if (h == 31) RS[127] = v[3];
    };

    // prologue: chunk 0 -> buf 0 (+ aligned nt bank copy)
    {
        floatx4 v[4];
#pragma unroll
        for (int j = 0; j < 4; ++j) v[j] = ntl(Fb + (size_t)j * 16 * NF);
#pragma unroll
        for (int j = 0; j < 4; ++j) {
            store_seg(j, 0, v[j]);
            short4v p;
            p[0] = f2bf(v[j][0]); p[1] = f2bf(v[j][1]);
            p[2] = f2bf(v[j][2]); p[3] = f2bf(v[j][3]);
            *(short4v*)&Bs[0][rrow + 16 * j][rcol] = p;
        }
    }
    __syncthreads();

    int cur = 0;
    for (int t = 0; t < 16; ++t) {
        int k0 = t * 128;
        floatx4 w[4];
        if (t < 15) {
            int k1 = k0 + 128;
#pragma unroll
            for (int j = 0; j < 4; ++j)
                w[j] = ntl(Fb + (size_t)j * 16 * NF + k1);
        }
        // ---- compute on Bs[cur] ----
#pragma unroll
        for (int kk = 0; kk < 4; ++kk) {
            short8 a0 = *(const short8*)(A0 + (t * 4 + kk) * 512);
            short8 a1 = *(const short8*)(A1 + (t * 4 + kk) * 512);
            short8 b0 = *(const short8*)&Bs[cur][l15][kk * 32 + lg * 8];
            short8 b1 = *(const short8*)&Bs[cur][16 + l15][kk * 32 + lg * 8];
            short8 b2 = *(const short8*)&Bs[cur][32 + l15][kk * 32 + lg * 8];
            short8 b3 = *(const short8*)&Bs[cur][48 + l15][kk * 32 + lg * 8];
            acc[0][0] = __builtin_amdgcn_mfma_f32_16x16x32_bf16(a0, b0, acc[0][0], 0, 0, 0);
            acc[0][1] = __builtin_amdgcn_mfma_f32_16x16x32_bf16(a0, b1, acc[0][1], 0, 0, 0);
            acc[0][2] = __builtin_amdgcn_mfma_f32_16x16x32_bf16(a0, b2, acc[0][2], 0, 0, 0);
            acc[0][3] = __builtin_amdgcn_mfma_f32_16x16x32_bf16(a0, b3, acc[0][3], 0, 0, 0);
            acc[1][0] = __builtin_amdgcn_mfma_f32_16x16x32_bf16(a1, b0, acc[1][0], 0, 0, 0);
            acc[1][1] = __builtin_amdgcn_mfma_f32_16x16x32_bf16(a1, b1, acc[1][1], 0, 0, 0);
            acc[1][2] = __builtin_amdgcn_mfma_f32_16x16x32_bf16(a1, b2, acc[1][2], 0, 0, 0);
            acc[1][3] = __builtin_amdgcn_mfma_f32_16x16x32_bf16(a1, b3, acc[1][3], 0, 0, 0);
        }
        // ---- stage chunk t+1 into buf cur^1 (+ aligned nt bank copy) ----
        if (t < 15) {
            int k1 = k0 + 128;
#pragma unroll
            for (int j = 0; j < 4; ++j) {
                store_seg(j, k1, w[j]);
                short4v p;
                p[0] = f2bf(w[j][0]); p[1] = f2bf(w[j][1]);
                p[2] = f2bf(w[j][2]); p[3] = f2bf(w[j][3]);
                *(short4v*)&Bs[cur ^ 1][rrow + 16 * j][rcol] = p;
            }
        }
        __syncthreads();
        cur ^= 1;
    }

    // ---- epilogue: per-row sum of exp(acc * 20) over this block's 64 cols ----
    float rs[2][4];
#pragma unroll
    for (int mf = 0; mf < 2; ++mf)
#pragma unroll
        for (int r = 0; r < 4; ++r) rs[mf][r] = 0.f;
#pragma unroll
    for (int mf = 0; mf < 2; ++mf)
#pragma unroll
        for (int nf = 0; nf < 4; ++nf)
#pragma unroll
            for (int r = 0; r < 4; ++r)
                rs[mf][r] += __expf(acc[mf][nf][r] * TEMP_INV);
#pragma unroll
    for (int mf = 0; mf < 2; ++mf)
#pragma unroll
        for (int r = 0; r < 4; ++r) {
            float v = rs[mf][r];
            v += __shfl_xor(v, 1);
            v += __shfl_xor(v, 2);
            v += __shfl_xor(v, 4);
            v += __shfl_xor(v, 8);
            rs[mf][r] = v;
        }
    if (l15 == 0) {
        int base = (bank * 512 + blockIdx.x) * 256;
#pragma unroll
        for (int mf = 0; mf < 2; ++mf)
#pragma unroll
            for (int r = 0; r < 4; ++r)
                spart[base + wave * 32 + mf * 16 + lg * 4 + r] = rs[mf][r];
    }
}

// grid (256, 3), block 256: parallel reduction of 512 sumexp partials
// per (bank,row). Writes per-(bank,row) CE+MSE term.
__global__ __launch_bounds__(256) void k_red(
    const float* spart, const float* tgt, const float* ldp, float* term) {
    int r = blockIdx.x, bank = blockIdx.y, j = threadIdx.x;
    __shared__ float red[8];
    float s = spart[(size_t)(bank * 512 + j) * 256 + r]
            + spart[(size_t)(bank * 512 + 256 + j) * 256 + r];
    float S = blockSum(s, red);
    if (j == 0)
        term[bank * 256 + r] = 0.5f * (logf(S) - tgt[bank * 256 + r] + ldp[bank * 256 + r]);
}

// single block 256: final sum
__global__ __launch_bounds__(256) void k_final(const float* term, float* out) {
    __shared__ float red[8];
    int r = threadIdx.x;
    float p = term[r] + term[256 + r] + term[512 + r];
    float tot = blockSum(p, red);
    if (r == 0) out[0] = tot / 256.0f;
}

// grid (256, 3), block 256: sequential EMA chains, first-occurrence block owns
// the full duplicate chain of its target. Runs last (overwrites copied rows).
__global__ __launch_bounds__(256) void k_ema(
    const float* f0, const float* f1, const float* f2,
    const float* xn, const int* targets, const int* epoch, float* outb) {
    int i = blockIdx.x, bank = blockIdx.y;
    __shared__ int tg[256];
    __shared__ float red[8];
    int tid = threadIdx.x;
    tg[tid] = targets[tid];
    __syncthreads();
    int y = tg[i];
    bool first = true;
    for (int j = 0; j < i; ++j) if (tg[j] == y) first = false;
    if (!first) return;   // uniform exit
    float m = (epoch[0] == -1) ? 1.0f : MOM;
    const float* F = bank == 0 ? f0 : bank == 1 ? f1 : f2;
    const float* Xn = xn + (size_t)bank * BB * NF;
    float r[8];
    const float* fr = F + (size_t)y * NF + tid * 8;
#pragma unroll
    for (int t = 0; t < 8; ++t) r[t] = fr[t];
    for (int j = i; j < 256; ++j) {
        if (tg[j] != y) continue;   // uniform
        const float* xr = Xn + (size_t)j * NF + tid * 8;
        float ss = 0.f;
#pragma unroll
        for (int t = 0; t < 8; ++t) {
            r[t] = m * r[t] + (1.0f - m) * xr[t];
            ss += r[t] * r[t];
        }
        float tot = blockSum(ss, red);
        float inv = 1.0f / sqrtf(tot);
#pragma unroll
        for (int t = 0; t < 8; ++t) r[t] *= inv;
    }
    float* o = outb + (size_t)bank * ((size_t)NS * NF) + (size_t)y * NF + tid * 8;
#pragma unroll
    for (int t = 0; t < 8; ++t) o[t] = r[t];
}

extern "C" void kernel_launch(void* const* d_in, const int* in_sizes, int n_in,
                              void* d_out, int out_size, void* d_ws, size_t ws_size,
                              hipStream_t stream) {
    const float* i0 = (const float*)d_in[0];
    const float* i1 = (const float*)d_in[1];
    const float* i2 = (const float*)d_in[2];
    const float* i3 = (const float*)d_in[3];
    const float* i4 = (const float*)d_in[4];
    const float* i5 = (const float*)d_in[5];
    const int* targets = (const int*)d_in[6];
    const int* epoch = (const int*)d_in[7];
    const float* f0 = (const float*)d_in[8];
    const float* f1 = (const float*)d_in[9];
    const float* f2 = (const float*)d_in[10];

    float* out = (float*)d_out;
    float* outb = out + 1;   // bank region (4B-aligned only)

    float* ws = (float*)d_ws;
    float* xn = ws;                               // 3*256*2048 f32 (students only)
    short* xb = (short*)(ws + 3 * BB * NF);       // 3*256*2048 bf16 (fragment order)
    float* spart = ws + 3 * BB * NF + (3 * BB * NF) / 2;  // 3*512*256 f32
    float* tgt = spart + 3 * 512 * 256;           // 768
    float* ldp = tgt + 768;                       // 768
    float* term = ldp + 768;                      // 768

    k_norm_ld<<<dim3(256, 3), 256, 0, stream>>>(i0, i1, i2, i3, i4, i5,
                                                f0, f1, f2, targets,
                                                xn, xb, ldp, tgt);
    k_gemm<<<dim3(512, 3), 512, 0, stream>>>(f0, f1, f2, xb, outb, spart);
    k_red<<<dim3(256, 3), 256, 0, stream>>>(spart, tgt, ldp, term);
    k_final<<<1, 256, 0, stream>>>(term, out);
    k_ema<<<dim3(256, 3), 256, 0, stream>>>(f0, f1, f2, xn, targets, epoch, outb);
}

// Round 20
// 416.228 us; speedup vs baseline: 1.0229x; 1.0229x over previous
//
#include <hip/hip_runtime.h>
#include <hip/hip_bf16.h>
#include <math.h>

#define NF 2048
#define NS 32768
#define BB 256
#define TEMP_INV 20.0f
#define MOM 0.2f

typedef __attribute__((ext_vector_type(4))) float floatx4;
typedef __attribute__((ext_vector_type(8))) short short8;
typedef __attribute__((ext_vector_type(4))) short short4v;

__device__ inline short f2bf(float f) {
    return __builtin_bit_cast(short, __float2bfloat16(f));
}

// Non-temporal 16B store (used at 16B-ALIGNED addresses only).
__device__ inline void st4u(float* p, floatx4 v) {
    asm volatile("global_store_dwordx4 %0, %1, off nt"
                 :: "v"(p), "v"(v));
}

// Non-temporal feature load: zero-reuse stream must NOT allocate in L2,
// so the 1MB A-matrix stays L2-resident (A is re-read 512x per bank).
__device__ inline floatx4 ntl(const float* p) {
    return __builtin_nontemporal_load(reinterpret_cast<const floatx4*>(p));
}

// Block-wide sum with broadcast to all threads. Deterministic order.
__device__ float blockSum(float v, float* s) {
    int lane = threadIdx.x & 63;
    int w = threadIdx.x >> 6;
    int nw = blockDim.x >> 6;
#pragma unroll
    for (int m = 32; m >= 1; m >>= 1) v += __shfl_xor(v, m);
    __syncthreads();
    if (lane == 0) s[w] = v;
    __syncthreads();
    float tot = s[0];
    for (int i = 1; i < nw; ++i) tot += s[i];
    return tot;
}

// grid (256, 3), block 256. Pair p: student d_in[p], teacher d_in[p+3].
// Writes student xn (f32), fragment-order bf16 xb, and ld term.
// Teacher normalized rows are NOT stored (only used for ld, computed here).
__global__ __launch_bounds__(256) void k_norm_ld(
    const float* i0, const float* i1, const float* i2,
    const float* i3, const float* i4, const float* i5,
    float* xn, short* xb, float* ldp) {
    int p = blockIdx.y;
    int b = blockIdx.x;
    const float* S = (p == 0 ? i0 : p == 1 ? i1 : i2) + (size_t)b * NF;
    const float* T = (p == 0 ? i3 : p == 1 ? i4 : i5) + (size_t)b * NF;
    __shared__ float red[8];
    int tid = threadIdx.x;

    float4 s0 = ((const float4*)S)[tid * 2];
    float4 s1 = ((const float4*)S)[tid * 2 + 1];
    float4 t0 = ((const float4*)T)[tid * 2];
    float4 t1 = ((const float4*)T)[tid * 2 + 1];

    float ssS = s0.x*s0.x + s0.y*s0.y + s0.z*s0.z + s0.w*s0.w
              + s1.x*s1.x + s1.y*s1.y + s1.z*s1.z + s1.w*s1.w;
    float ssT = t0.x*t0.x + t0.y*t0.y + t0.z*t0.z + t0.w*t0.w
              + t1.x*t1.x + t1.y*t1.y + t1.z*t1.z + t1.w*t1.w;
    float totS = blockSum(ssS, red);
    float totT = blockSum(ssT, red);
    float invS = 1.0f / sqrtf(totS);
    float invT = 1.0f / sqrtf(totT);

    float xs[8] = { s0.x*invS, s0.y*invS, s0.z*invS, s0.w*invS,
                    s1.x*invS, s1.y*invS, s1.z*invS, s1.w*invS };
    float xt[8] = { t0.x*invT, t0.y*invT, t0.z*invT, t0.w*invT,
                    t1.x*invT, t1.y*invT, t1.z*invT, t1.w*invT };

    float* xns = xn + (size_t)p * BB * NF + (size_t)b * NF + tid * 8;
    ((float4*)xns)[0] = make_float4(xs[0], xs[1], xs[2], xs[3]);
    ((float4*)xns)[1] = make_float4(xs[4], xs[5], xs[6], xs[7]);

    short8 bfv;
#pragma unroll
    for (int j = 0; j < 8; ++j) bfv[j] = f2bf(xs[j]);
    {
        int rb = b >> 4, l15r = b & 15;
        int kb = tid >> 2, lg = tid & 3;
        size_t flat = ((size_t)(rb * 64 + kb) * 64 + lg * 16 + l15r) * 8;
        *(short8*)(xb + (size_t)p * BB * NF + flat) = bfv;
    }

    float ld = 0;
#pragma unroll
    for (int j = 0; j < 8; ++j) { float d = xs[j] - xt[j]; ld += d * d; }
    float ldt = blockSum(ld, red);
    if (tid == 0) ldp[p * BB + b] = ldt;
}

// grid (512, 3), block 512 (8 waves), 2 blocks/CU. 64 feature rows, full M.
// R17 structure + 2-DEEP register prefetch: at iter t issue chunk t+2's
// loads (wB), compute on Bs[cur], then stage wA (chunk t+1, loaded a full
// iteration ago -> HBM latency fully hidden). nt loads (A stays L2-hot),
// in-register realigned nt stores.
__global__ __launch_bounds__(512, 2) void k_gemm(
    const float* f0, const float* f1, const float* f2,
    const short* xb, float* outb, float* spart) {
    int bank = blockIdx.y;
    const float* F = bank == 0 ? f0 : bank == 1 ? f1 : f2;
    const short* X = xb + (size_t)bank * BB * NF;
    float* C = outb + (size_t)bank * ((size_t)NS * NF);
    int n0 = blockIdx.x * 64;

    __shared__ short Bs[2][64][136];   // 2 x 17408B

    int tid = threadIdx.x;
    int lane = tid & 63, wave = tid >> 6;
    int l15 = lane & 15, lg = lane >> 4;
    int rrow = tid >> 5;               // 0..15
    int h = tid & 31;                  // lane within half-wave = chunk index
    int rcol = h * 4;                  // float col, lane-contiguous

    const float* Fb = F + (size_t)(n0 + rrow) * NF + rcol;
    float* CbR = C + (size_t)(n0 + rrow) * NF;   // row base (no col)
    // fragment-ordered A: rb0 = wave*2, rb1 = wave*2+1; stride per kb = 512
    const short* A0 = X + (size_t)(wave * 2) * 32768 + (size_t)lane * 8;
    const short* A1 = A0 + 32768;

    floatx4 acc[2][4];
#pragma unroll
    for (int mf = 0; mf < 2; ++mf)
#pragma unroll
        for (int nf = 0; nf < 4; ++nf) acc[mf][nf] = (floatx4){0.f, 0.f, 0.f, 0.f};

    // aligned copy-out of one row-segment chunk (j, kbase) from regs v
    auto store_seg = [&](int j, int kbase, floatx4 v) {
        floatx4 st;
        st[0] = v[3];
        st[1] = __shfl_down(v[0], 1);
        st[2] = __shfl_down(v[1], 1);
        st[3] = __shfl_down(v[2], 1);
        float* RS = CbR + (size_t)j * 16 * NF + kbase;
        if (h < 31) st4u(RS + 4 * h + 3, st);
        if (h == 0) { RS[0] = v[0]; RS[1] = v[1]; RS[2] = v[2]; }
        else if (h == 31) RS[127] = v[3];
    };

    // prologue: stage chunk 0 directly; prefetch chunk 1 into wA
    {
        floatx4 v[4];
#pragma unroll
        for (int j = 0; j < 4; ++j) v[j] = ntl(Fb + (size_t)j * 16 * NF);
#pragma unroll
        for (int j = 0; j < 4; ++j) {
            store_seg(j, 0, v[j]);
            short4v p;
            p[0] = f2bf(v[j][0]); p[1] = f2bf(v[j][1]);
            p[2] = f2bf(v[j][2]); p[3] = f2bf(v[j][3]);
            *(short4v*)&Bs[0][rrow + 16 * j][rcol] = p;
        }
    }
    floatx4 wA[4];
#pragma unroll
    for (int j = 0; j < 4; ++j) wA[j] = ntl(Fb + (size_t)j * 16 * NF + 128);
    __syncthreads();

    int cur = 0;
    for (int t = 0; t < 16; ++t) {
        // ---- issue chunk t+2 loads (2-deep prefetch) ----
        floatx4 wB[4];
        if (t < 14) {
            int k2 = (t + 2) * 128;
#pragma unroll
            for (int j = 0; j < 4; ++j)
                wB[j] = ntl(Fb + (size_t)j * 16 * NF + k2);
        }
        // ---- compute on Bs[cur] ----
#pragma unroll
        for (int kk = 0; kk < 4; ++kk) {
            short8 a0 = *(const short8*)(A0 + (t * 4 + kk) * 512);
            short8 a1 = *(const short8*)(A1 + (t * 4 + kk) * 512);
            short8 b0 = *(const short8*)&Bs[cur][l15][kk * 32 + lg * 8];
            short8 b1 = *(const short8*)&Bs[cur][16 + l15][kk * 32 + lg * 8];
            short8 b2 = *(const short8*)&Bs[cur][32 + l15][kk * 32 + lg * 8];
            short8 b3 = *(const short8*)&Bs[cur][48 + l15][kk * 32 + lg * 8];
            acc[0][0] = __builtin_amdgcn_mfma_f32_16x16x32_bf16(a0, b0, acc[0][0], 0, 0, 0);
            acc[0][1] = __builtin_amdgcn_mfma_f32_16x16x32_bf16(a0, b1, acc[0][1], 0, 0, 0);
            acc[0][2] = __builtin_amdgcn_mfma_f32_16x16x32_bf16(a0, b2, acc[0][2], 0, 0, 0);
            acc[0][3] = __builtin_amdgcn_mfma_f32_16x16x32_bf16(a0, b3, acc[0][3], 0, 0, 0);
            acc[1][0] = __builtin_amdgcn_mfma_f32_16x16x32_bf16(a1, b0, acc[1][0], 0, 0, 0);
            acc[1][1] = __builtin_amdgcn_mfma_f32_16x16x32_bf16(a1, b1, acc[1][1], 0, 0, 0);
            acc[1][2] = __builtin_amdgcn_mfma_f32_16x16x32_bf16(a1, b2, acc[1][2], 0, 0, 0);
            acc[1][3] = __builtin_amdgcn_mfma_f32_16x16x32_bf16(a1, b3, acc[1][3], 0, 0, 0);
        }
        // ---- stage wA (chunk t+1) into Bs[cur^1] (+ aligned nt copy) ----
        if (t < 15) {
            int k1 = (t + 1) * 128;
#pragma unroll
            for (int j = 0; j < 4; ++j) {
                store_seg(j, k1, wA[j]);
                short4v p;
                p[0] = f2bf(wA[j][0]); p[1] = f2bf(wA[j][1]);
                p[2] = f2bf(wA[j][2]); p[3] = f2bf(wA[j][3]);
                *(short4v*)&Bs[cur ^ 1][rrow + 16 * j][rcol] = p;
            }
        }
        __syncthreads();
#pragma unroll
        for (int j = 0; j < 4; ++j) wA[j] = wB[j];
        cur ^= 1;
    }

    // ---- epilogue: per-row sum of exp(acc * 20) over this block's 64 cols ----
    float rs[2][4];
#pragma unroll
    for (int mf = 0; mf < 2; ++mf)
#pragma unroll
        for (int r = 0; r < 4; ++r) rs[mf][r] = 0.f;
#pragma unroll
    for (int mf = 0; mf < 2; ++mf)
#pragma unroll
        for (int nf = 0; nf < 4; ++nf)
#pragma unroll
            for (int r = 0; r < 4; ++r)
                rs[mf][r] += __expf(acc[mf][nf][r] * TEMP_INV);
#pragma unroll
    for (int mf = 0; mf < 2; ++mf)
#pragma unroll
        for (int r = 0; r < 4; ++r) {
            float v = rs[mf][r];
            v += __shfl_xor(v, 1);
            v += __shfl_xor(v, 2);
            v += __shfl_xor(v, 4);
            v += __shfl_xor(v, 8);
            rs[mf][r] = v;
        }
    if (l15 == 0) {
        int base = (bank * 512 + blockIdx.x) * 256;
#pragma unroll
        for (int mf = 0; mf < 2; ++mf)
#pragma unroll
            for (int r = 0; r < 4; ++r)
                spart[base + wave * 32 + mf * 16 + lg * 4 + r] = rs[mf][r];
    }
}

// grid (256, 3), block 256: exact f32 target logit dot(x_b, f[y_b]) * 20.
// Runs AFTER k_gemm so the gathered F rows are L3-warm from the GEMM stream.
__global__ __launch_bounds__(256) void k_tgt(
    const float* f0, const float* f1, const float* f2,
    const float* xn, const int* targets, float* tgt) {
    int b = blockIdx.x, bank = blockIdx.y;
    const float* F = (bank == 0 ? f0 : bank == 1 ? f1 : f2) + (size_t)targets[b] * NF;
    const float* Xr = xn + (size_t)bank * BB * NF + (size_t)b * NF;
    __shared__ float red[8];
    int tid = threadIdx.x;
    float4 x0 = ((const float4*)Xr)[tid * 2];
    float4 x1 = ((const float4*)Xr)[tid * 2 + 1];
    float4 g0 = ((const float4*)F)[tid * 2];
    float4 g1 = ((const float4*)F)[tid * 2 + 1];
    float s = x0.x*g0.x + x0.y*g0.y + x0.z*g0.z + x0.w*g0.w
            + x1.x*g1.x + x1.y*g1.y + x1.z*g1.z + x1.w*g1.w;
    float tot = blockSum(s, red);
    if (tid == 0) tgt[bank * BB + b] = tot * TEMP_INV;
}

// grid (256, 3), block 256: parallel reduction of 512 sumexp partials
// per (bank,row). Writes per-(bank,row) CE+MSE term.
__global__ __launch_bounds__(256) void k_red(
    const float* spart, const float* tgt, const float* ldp, float* term) {
    int r = blockIdx.x, bank = blockIdx.y, j = threadIdx.x;
    __shared__ float red[8];
    float s = spart[(size_t)(bank * 512 + j) * 256 + r]
            + spart[(size_t)(bank * 512 + 256 + j) * 256 + r];
    float S = blockSum(s, red);
    if (j == 0)
        term[bank * 256 + r] = 0.5f * (logf(S) - tgt[bank * 256 + r] + ldp[bank * 256 + r]);
}

// single block 256: final sum
__global__ __launch_bounds__(256) void k_final(const float* term, float* out) {
    __shared__ float red[8];
    int r = threadIdx.x;
    float p = term[r] + term[256 + r] + term[512 + r];
    float tot = blockSum(p, red);
    if (r == 0) out[0] = tot / 256.0f;
}

// grid (256, 3), block 256: sequential EMA chains, first-occurrence block owns
// the full duplicate chain of its target. Runs last (overwrites copied rows).
__global__ __launch_bounds__(256) void k_ema(
    const float* f0, const float* f1, const float* f2,
    const float* xn, const int* targets, const int* epoch, float* outb) {
    int i = blockIdx.x, bank = blockIdx.y;
    __shared__ int tg[256];
    __shared__ float red[8];
    int tid = threadIdx.x;
    tg[tid] = targets[tid];
    __syncthreads();
    int y = tg[i];
    bool first = true;
    for (int j = 0; j < i; ++j) if (tg[j] == y) first = false;
    if (!first) return;   // uniform exit
    float m = (epoch[0] == -1) ? 1.0f : MOM;
    const float* F = bank == 0 ? f0 : bank == 1 ? f1 : f2;
    const float* Xn = xn + (size_t)bank * BB * NF;
    float r[8];
    const float* fr = F + (size_t)y * NF + tid * 8;
#pragma unroll
    for (int t = 0; t < 8; ++t) r[t] = fr[t];
    for (int j = i; j < 256; ++j) {
        if (tg[j] != y) continue;   // uniform
        const float* xr = Xn + (size_t)j * NF + tid * 8;
        float ss = 0.f;
#pragma unroll
        for (int t = 0; t < 8; ++t) {
            r[t] = m * r[t] + (1.0f - m) * xr[t];
            ss += r[t] * r[t];
        }
        float tot = blockSum(ss, red);
        float inv = 1.0f / sqrtf(tot);
#pragma unroll
        for (int t = 0; t < 8; ++t) r[t] *= inv;
    }
    float* o = outb + (size_t)bank * ((size_t)NS * NF) + (size_t)y * NF + tid * 8;
#pragma unroll
    for (int t = 0; t < 8; ++t) o[t] = r[t];
}

extern "C" void kernel_launch(void* const* d_in, const int* in_sizes, int n_in,
                              void* d_out, int out_size, void* d_ws, size_t ws_size,
                              hipStream_t stream) {
    const float* i0 = (const float*)d_in[0];
    const float* i1 = (const float*)d_in[1];
    const float* i2 = (const float*)d_in[2];
    const float* i3 = (const float*)d_in[3];
    const float* i4 = (const float*)d_in[4];
    const float* i5 = (const float*)d_in[5];
    const int* targets = (const int*)d_in[6];
    const int* epoch = (const int*)d_in[7];
    const float* f0 = (const float*)d_in[8];
    const float* f1 = (const float*)d_in[9];
    const float* f2 = (const float*)d_in[10];

    float* out = (float*)d_out;
    float* outb = out + 1;   // bank region (4B-aligned only)

    float* ws = (float*)d_ws;
    float* xn = ws;                               // 3*256*2048 f32 (students only)
    short* xb = (short*)(ws + 3 * BB * NF);       // 3*256*2048 bf16 (fragment order)
    float* spart = ws + 3 * BB * NF + (3 * BB * NF) / 2;  // 3*512*256 f32
    float* tgt = spart + 3 * 512 * 256;           // 768
    float* ldp = tgt + 768;                       // 768
    float* term = ldp + 768;                      // 768

    k_norm_ld<<<dim3(256, 3), 256, 0, stream>>>(i0, i1, i2, i3, i4, i5,
                                                xn, xb, ldp);
    k_gemm<<<dim3(512, 3), 512, 0, stream>>>(f0, f1, f2, xb, outb, spart);
    k_tgt<<<dim3(256, 3), 256, 0, stream>>>(f0, f1, f2, xn, targets, tgt);
    k_red<<<dim3(256, 3), 256, 0, stream>>>(spart, tgt, ldp, term);
    k_final<<<1, 256, 0, stream>>>(term, out);
    k_ema<<<dim3(256, 3), 256, 0, stream>>>(f0, f1, f2, xn, targets, epoch, outb);
}

// Round 21
// 391.875 us; speedup vs baseline: 1.0865x; 1.0621x over previous
//
#include <hip/hip_runtime.h>
#include <hip/hip_bf16.h>
#include <math.h>

#define NF 2048
#define NS 32768
#define BB 256
#define TEMP_INV 20.0f
#define MOM 0.2f

typedef __attribute__((ext_vector_type(4))) float floatx4;
typedef __attribute__((ext_vector_type(8))) short short8;
typedef __attribute__((ext_vector_type(4))) short short4v;

__device__ inline short f2bf(float f) {
    return __builtin_bit_cast(short, __float2bfloat16(f));
}

// Non-temporal 16B store (used at 16B-ALIGNED addresses only).
__device__ inline void st4u(float* p, floatx4 v) {
    asm volatile("global_store_dwordx4 %0, %1, off nt"
                 :: "v"(p), "v"(v));
}

// Non-temporal feature load: zero-reuse stream must NOT allocate in L2,
// so the 1MB A-matrix stays L2-resident (A is re-read 512x per bank).
__device__ inline floatx4 ntl(const float* p) {
    return __builtin_nontemporal_load(reinterpret_cast<const floatx4*>(p));
}

// Block-wide sum with broadcast to all threads. Deterministic order.
__device__ float blockSum(float v, float* s) {
    int lane = threadIdx.x & 63;
    int w = threadIdx.x >> 6;
    int nw = blockDim.x >> 6;
#pragma unroll
    for (int m = 32; m >= 1; m >>= 1) v += __shfl_xor(v, m);
    __syncthreads();
    if (lane == 0) s[w] = v;
    __syncthreads();
    float tot = s[0];
    for (int i = 1; i < nw; ++i) tot += s[i];
    return tot;
}

// grid (256, 3), block 256. Pair p: student d_in[p], teacher d_in[p+3].
// Writes student xn (f32), fragment-order bf16 xb, and ld term.
// Teacher normalized rows are NOT stored (only used for ld, computed here).
__global__ __launch_bounds__(256) void k_norm_ld(
    const float* i0, const float* i1, const float* i2,
    const float* i3, const float* i4, const float* i5,
    float* xn, short* xb, float* ldp) {
    int p = blockIdx.y;
    int b = blockIdx.x;
    const float* S = (p == 0 ? i0 : p == 1 ? i1 : i2) + (size_t)b * NF;
    const float* T = (p == 0 ? i3 : p == 1 ? i4 : i5) + (size_t)b * NF;
    __shared__ float red[8];
    int tid = threadIdx.x;

    float4 s0 = ((const float4*)S)[tid * 2];
    float4 s1 = ((const float4*)S)[tid * 2 + 1];
    float4 t0 = ((const float4*)T)[tid * 2];
    float4 t1 = ((const float4*)T)[tid * 2 + 1];

    float ssS = s0.x*s0.x + s0.y*s0.y + s0.z*s0.z + s0.w*s0.w
              + s1.x*s1.x + s1.y*s1.y + s1.z*s1.z + s1.w*s1.w;
    float ssT = t0.x*t0.x + t0.y*t0.y + t0.z*t0.z + t0.w*t0.w
              + t1.x*t1.x + t1.y*t1.y + t1.z*t1.z + t1.w*t1.w;
    float totS = blockSum(ssS, red);
    float totT = blockSum(ssT, red);
    float invS = 1.0f / sqrtf(totS);
    float invT = 1.0f / sqrtf(totT);

    float xs[8] = { s0.x*invS, s0.y*invS, s0.z*invS, s0.w*invS,
                    s1.x*invS, s1.y*invS, s1.z*invS, s1.w*invS };
    float xt[8] = { t0.x*invT, t0.y*invT, t0.z*invT, t0.w*invT,
                    t1.x*invT, t1.y*invT, t1.z*invT, t1.w*invT };

    float* xns = xn + (size_t)p * BB * NF + (size_t)b * NF + tid * 8;
    ((float4*)xns)[0] = make_float4(xs[0], xs[1], xs[2], xs[3]);
    ((float4*)xns)[1] = make_float4(xs[4], xs[5], xs[6], xs[7]);

    short8 bfv;
#pragma unroll
    for (int j = 0; j < 8; ++j) bfv[j] = f2bf(xs[j]);
    {
        int rb = b >> 4, l15r = b & 15;
        int kb = tid >> 2, lg = tid & 3;
        size_t flat = ((size_t)(rb * 64 + kb) * 64 + lg * 16 + l15r) * 8;
        *(short8*)(xb + (size_t)p * BB * NF + flat) = bfv;
    }

    float ld = 0;
#pragma unroll
    for (int j = 0; j < 8; ++j) { float d = xs[j] - xt[j]; ld += d * d; }
    float ldt = blockSum(ld, red);
    if (tid == 0) ldp[p * BB + b] = ldt;
}

// grid (512, 3), block 512 (8 waves), 2 blocks/CU. 64 feature rows, full M.
// R17 structure (1-deep prefetch, nt loads, nt stores) with LINE-COHERENT
// SHIFTED copy stores: lane h writes floats [4h-1, 4h+3) of each segment
// (st[0] = shfl_up(own v[3]); h==0 takes prevTail from the previous chunk).
// Row base is +4B, so RS+4h-1 is 64B-line-aligned at h%4==0 -> every
// interior 64B line is covered by 4 stores of ONE staging call (nt partial-
// line RMW amplification eliminated; only per-row head/tail remain partial).
__global__ __launch_bounds__(512, 2) void k_gemm(
    const float* f0, const float* f1, const float* f2,
    const short* xb, float* outb, float* spart) {
    int bank = blockIdx.y;
    const float* F = bank == 0 ? f0 : bank == 1 ? f1 : f2;
    const short* X = xb + (size_t)bank * BB * NF;
    float* C = outb + (size_t)bank * ((size_t)NS * NF);
    int n0 = blockIdx.x * 64;

    __shared__ short Bs[2][64][136];   // 2 x 17408B

    int tid = threadIdx.x;
    int lane = tid & 63, wave = tid >> 6;
    int l15 = lane & 15, lg = lane >> 4;
    int rrow = tid >> 5;               // 0..15
    int h = tid & 31;                  // lane within half-wave = chunk index
    int rcol = h * 4;                  // float col, lane-contiguous

    const float* Fb = F + (size_t)(n0 + rrow) * NF + rcol;
    float* CbR = C + (size_t)(n0 + rrow) * NF;   // row base (no col)
    // fragment-ordered A: rb0 = wave*2, rb1 = wave*2+1; stride per kb = 512
    const short* A0 = X + (size_t)(wave * 2) * 32768 + (size_t)lane * 8;
    const short* A1 = A0 + 32768;

    floatx4 acc[2][4];
#pragma unroll
    for (int mf = 0; mf < 2; ++mf)
#pragma unroll
        for (int nf = 0; nf < 4; ++nf) acc[mf][nf] = (floatx4){0.f, 0.f, 0.f, 0.f};

    float prevTail[4];

    // prologue: chunk 0 -> buf 0 (+ line-coherent nt copy, head scalars)
    {
        floatx4 v[4];
#pragma unroll
        for (int j = 0; j < 4; ++j) v[j] = ntl(Fb + (size_t)j * 16 * NF);
#pragma unroll
        for (int j = 0; j < 4; ++j) {
            floatx4 st;
            st[0] = __shfl_up(v[j][3], 1);
            st[1] = v[j][0]; st[2] = v[j][1]; st[3] = v[j][2];
            float* RS = CbR + (size_t)j * 16 * NF;   // kbase = 0
            if (h == 0) { RS[0] = v[j][0]; RS[1] = v[j][1]; RS[2] = v[j][2]; }
            else st4u(RS + 4 * h - 1, st);
            prevTail[j] = __shfl(v[j][3], 31, 32);
            short4v p;
            p[0] = f2bf(v[j][0]); p[1] = f2bf(v[j][1]);
            p[2] = f2bf(v[j][2]); p[3] = f2bf(v[j][3]);
            *(short4v*)&Bs[0][rrow + 16 * j][rcol] = p;
        }
    }
    __syncthreads();

    int cur = 0;
    for (int t = 0; t < 16; ++t) {
        int k0 = t * 128;
        floatx4 w[4];
        if (t < 15) {
            int k1 = k0 + 128;
#pragma unroll
            for (int j = 0; j < 4; ++j)
                w[j] = ntl(Fb + (size_t)j * 16 * NF + k1);
        }
        // ---- compute on Bs[cur] ----
#pragma unroll
        for (int kk = 0; kk < 4; ++kk) {
            short8 a0 = *(const short8*)(A0 + (t * 4 + kk) * 512);
            short8 a1 = *(const short8*)(A1 + (t * 4 + kk) * 512);
            short8 b0 = *(const short8*)&Bs[cur][l15][kk * 32 + lg * 8];
            short8 b1 = *(const short8*)&Bs[cur][16 + l15][kk * 32 + lg * 8];
            short8 b2 = *(const short8*)&Bs[cur][32 + l15][kk * 32 + lg * 8];
            short8 b3 = *(const short8*)&Bs[cur][48 + l15][kk * 32 + lg * 8];
            acc[0][0] = __builtin_amdgcn_mfma_f32_16x16x32_bf16(a0, b0, acc[0][0], 0, 0, 0);
            acc[0][1] = __builtin_amdgcn_mfma_f32_16x16x32_bf16(a0, b1, acc[0][1], 0, 0, 0);
            acc[0][2] = __builtin_amdgcn_mfma_f32_16x16x32_bf16(a0, b2, acc[0][2], 0, 0, 0);
            acc[0][3] = __builtin_amdgcn_mfma_f32_16x16x32_bf16(a0, b3, acc[0][3], 0, 0, 0);
            acc[1][0] = __builtin_amdgcn_mfma_f32_16x16x32_bf16(a1, b0, acc[1][0], 0, 0, 0);
            acc[1][1] = __builtin_amdgcn_mfma_f32_16x16x32_bf16(a1, b1, acc[1][1], 0, 0, 0);
            acc[1][2] = __builtin_amdgcn_mfma_f32_16x16x32_bf16(a1, b2, acc[1][2], 0, 0, 0);
            acc[1][3] = __builtin_amdgcn_mfma_f32_16x16x32_bf16(a1, b3, acc[1][3], 0, 0, 0);
        }
        // ---- stage chunk t+1 into buf cur^1 (+ line-coherent nt copy) ----
        if (t < 15) {
            int k1 = k0 + 128;
            bool last = (t == 14);
#pragma unroll
            for (int j = 0; j < 4; ++j) {
                floatx4 st;
                st[0] = __shfl_up(w[j][3], 1);
                if (h == 0) st[0] = prevTail[j];
                st[1] = w[j][0]; st[2] = w[j][1]; st[3] = w[j][2];
                float* RS = CbR + (size_t)j * 16 * NF + k1;
                st4u(RS + 4 * h - 1, st);
                if (last && h == 31) RS[127] = w[j][3];
                prevTail[j] = __shfl(w[j][3], 31, 32);
                short4v p;
                p[0] = f2bf(w[j][0]); p[1] = f2bf(w[j][1]);
                p[2] = f2bf(w[j][2]); p[3] = f2bf(w[j][3]);
                *(short4v*)&Bs[cur ^ 1][rrow + 16 * j][rcol] = p;
            }
        }
        __syncthreads();
        cur ^= 1;
    }

    // ---- epilogue: per-row sum of exp(acc * 20) over this block's 64 cols ----
    float rs[2][4];
#pragma unroll
    for (int mf = 0; mf < 2; ++mf)
#pragma unroll
        for (int r = 0; r < 4; ++r) rs[mf][r] = 0.f;
#pragma unroll
    for (int mf = 0; mf < 2; ++mf)
#pragma unroll
        for (int nf = 0; nf < 4; ++nf)
#pragma unroll
            for (int r = 0; r < 4; ++r)
                rs[mf][r] += __expf(acc[mf][nf][r] * TEMP_INV);
#pragma unroll
    for (int mf = 0; mf < 2; ++mf)
#pragma unroll
        for (int r = 0; r < 4; ++r) {
            float v = rs[mf][r];
            v += __shfl_xor(v, 1);
            v += __shfl_xor(v, 2);
            v += __shfl_xor(v, 4);
            v += __shfl_xor(v, 8);
            rs[mf][r] = v;
        }
    if (l15 == 0) {
        int base = (bank * 512 + blockIdx.x) * 256;
#pragma unroll
        for (int mf = 0; mf < 2; ++mf)
#pragma unroll
            for (int r = 0; r < 4; ++r)
                spart[base + wave * 32 + mf * 16 + lg * 4 + r] = rs[mf][r];
    }
}

// grid (256, 3), block 256: exact f32 target logit dot(x_b, f[y_b]) * 20.
// Runs AFTER k_gemm so the gathered F rows are L3-warm from the GEMM stream.
__global__ __launch_bounds__(256) void k_tgt(
    const float* f0, const float* f1, const float* f2,
    const float* xn, const int* targets, float* tgt) {
    int b = blockIdx.x, bank = blockIdx.y;
    const float* F = (bank == 0 ? f0 : bank == 1 ? f1 : f2) + (size_t)targets[b] * NF;
    const float* Xr = xn + (size_t)bank * BB * NF + (size_t)b * NF;
    __shared__ float red[8];
    int tid = threadIdx.x;
    float4 x0 = ((const float4*)Xr)[tid * 2];
    float4 x1 = ((const float4*)Xr)[tid * 2 + 1];
    float4 g0 = ((const float4*)F)[tid * 2];
    float4 g1 = ((const float4*)F)[tid * 2 + 1];
    float s = x0.x*g0.x + x0.y*g0.y + x0.z*g0.z + x0.w*g0.w
            + x1.x*g1.x + x1.y*g1.y + x1.z*g1.z + x1.w*g1.w;
    float tot = blockSum(s, red);
    if (tid == 0) tgt[bank * BB + b] = tot * TEMP_INV;
}

// grid (256, 3), block 256: parallel reduction of 512 sumexp partials
// per (bank,row). Writes per-(bank,row) CE+MSE term.
__global__ __launch_bounds__(256) void k_red(
    const float* spart, const float* tgt, const float* ldp, float* term) {
    int r = blockIdx.x, bank = blockIdx.y, j = threadIdx.x;
    __shared__ float red[8];
    float s = spart[(size_t)(bank * 512 + j) * 256 + r]
            + spart[(size_t)(bank * 512 + 256 + j) * 256 + r];
    float S = blockSum(s, red);
    if (j == 0)
        term[bank * 256 + r] = 0.5f * (logf(S) - tgt[bank * 256 + r] + ldp[bank * 256 + r]);
}

// single block 256: final sum
__global__ __launch_bounds__(256) void k_final(const float* term, float* out) {
    __shared__ float red[8];
    int r = threadIdx.x;
    float p = term[r] + term[256 + r] + term[512 + r];
    float tot = blockSum(p, red);
    if (r == 0) out[0] = tot / 256.0f;
}

// grid (256, 3), block 256: sequential EMA chains, first-occurrence block owns
// the full duplicate chain of its target. Runs last (overwrites copied rows).
__global__ __launch_bounds__(256) void k_ema(
    const float* f0, const float* f1, const float* f2,
    const float* xn, const int* targets, const int* epoch, float* outb) {
    int i = blockIdx.x, bank = blockIdx.y;
    __shared__ int tg[256];
    __shared__ float red[8];
    int tid = threadIdx.x;
    tg[tid] = targets[tid];
    __syncthreads();
    int y = tg[i];
    bool first = true;
    for (int j = 0; j < i; ++j) if (tg[j] == y) first = false;
    if (!first) return;   // uniform exit
    float m = (epoch[0] == -1) ? 1.0f : MOM;
    const float* F = bank == 0 ? f0 : bank == 1 ? f1 : f2;
    const float* Xn = xn + (size_t)bank * BB * NF;
    float r[8];
    const float* fr = F + (size_t)y * NF + tid * 8;
#pragma unroll
    for (int t = 0; t < 8; ++t) r[t] = fr[t];
    for (int j = i; j < 256; ++j) {
        if (tg[j] != y) continue;   // uniform
        const float* xr = Xn + (size_t)j * NF + tid * 8;
        float ss = 0.f;
#pragma unroll
        for (int t = 0; t < 8; ++t) {
            r[t] = m * r[t] + (1.0f - m) * xr[t];
            ss += r[t] * r[t];
        }
        float tot = blockSum(ss, red);
        float inv = 1.0f / sqrtf(tot);
#pragma unroll
        for (int t = 0; t < 8; ++t) r[t] *= inv;
    }
    float* o = outb + (size_t)bank * ((size_t)NS * NF) + (size_t)y * NF + tid * 8;
#pragma unroll
    for (int t = 0; t < 8; ++t) o[t] = r[t];
}

extern "C" void kernel_launch(void* const* d_in, const int* in_sizes, int n_in,
                              void* d_out, int out_size, void* d_ws, size_t ws_size,
                              hipStream_t stream) {
    const float* i0 = (const float*)d_in[0];
    const float* i1 = (const float*)d_in[1];
    const float* i2 = (const float*)d_in[2];
    const float* i3 = (const float*)d_in[3];
    const float* i4 = (const float*)d_in[4];
    const float* i5 = (const float*)d_in[5];
    const int* targets = (const int*)d_in[6];
    const int* epoch = (const int*)d_in[7];
    const float* f0 = (const float*)d_in[8];
    const float* f1 = (const float*)d_in[9];
    const float* f2 = (const float*)d_in[10];

    float* out = (float*)d_out;
    float* outb = out + 1;   // bank region (4B-aligned only)

    float* ws = (float*)d_ws;
    float* xn = ws;                               // 3*256*2048 f32 (students only)
    short* xb = (short*)(ws + 3 * BB * NF);       // 3*256*2048 bf16 (fragment order)
    float* spart = ws + 3 * BB * NF + (3 * BB * NF) / 2;  // 3*512*256 f32
    float* tgt = spart + 3 * 512 * 256;           // 768
    float* ldp = tgt + 768;                       // 768
    float* term = ldp + 768;                      // 768

    k_norm_ld<<<dim3(256, 3), 256, 0, stream>>>(i0, i1, i2, i3, i4, i5,
                                                xn, xb, ldp);
    k_gemm<<<dim3(512, 3), 512, 0, stream>>>(f0, f1, f2, xb, outb, spart);
    k_tgt<<<dim3(256, 3), 256, 0, stream>>>(f0, f1, f2, xn, targets, tgt);
    k_red<<<dim3(256, 3), 256, 0, stream>>>(spart, tgt, ldp, term);
    k_final<<<1, 256, 0, stream>>>(term, out);
    k_ema<<<dim3(256, 3), 256, 0, stream>>>(f0, f1, f2, xn, targets, epoch, outb);
}